// Round 4
// baseline (162.736 us; speedup 1.0000x reference)
//
#include <hip/hip_runtime.h>

typedef __attribute__((ext_vector_type(8))) short short8;
typedef __attribute__((ext_vector_type(4))) float floatx4;
typedef unsigned int uint;
typedef unsigned short ushort;
typedef __attribute__((ext_vector_type(4))) uint uintx4;

#define NTOK   8192
#define DIN    1024
#define DOUT   1024
#define NJ     96        // 84 decision nodes (12 trees x 7) + 12 gates
#define TOKPB  16        // tokens per block -> 512 blocks (2/CU: phase overlap)
#define XSTR   136       // LDS row stride (bf16 elems) for x/w tiles
#define DSTR   97        // decis LDS row stride (f32)
#define SSTR   85        // sdec LDS row stride (f32)
#define RSTR   104       // routed LDS tile row stride (bf16)
#define LOT_H  (DOUT * NJ)

static __device__ inline ushort f2b(float f) {
    uint u = __builtin_bit_cast(uint, f);
    u = u + 0x7fffu + ((u >> 16) & 1u);   // RNE
    return (ushort)(u >> 16);
}
static __device__ inline uint pack2(float a, float b) {
    return (uint)f2b(a) | ((uint)f2b(b) << 16);
}

// ---------------------------------------------------------------------------
// k_prep: f32 -> bf16.  lo [3][96][1024] -> lot [3][1024][96] (transposed);
// dw[84][1024] ++ gw[12][1024] -> wcat[96][1024].
// ---------------------------------------------------------------------------
__global__ __launch_bounds__(256) void k_prep(const float* __restrict__ lo,
                                              const float* __restrict__ dw,
                                              const float* __restrict__ gw,
                                              ushort* __restrict__ lot,
                                              ushort* __restrict__ wcat) {
    int i = blockIdx.x * 256 + threadIdx.x;
    if (i < 3 * LOT_H) {
        int h = i / LOT_H;
        int rem = i - h * LOT_H;
        int k = rem >> 10;
        int d = rem & 1023;
        lot[h * LOT_H + d * NJ + k] = f2b(lo[i]);
    } else {
        int j = i - 3 * LOT_H;
        int r = j >> 10, c = j & 1023;
        float v = (r < 84) ? dw[r * DIN + c] : gw[(r - 84) * DIN + c];
        wcat[j] = f2b(v);
    }
}

// ---------------------------------------------------------------------------
// k_fused (16 tokens/block, 512 blocks = 2 blocks/CU):
//   phase 1: decisions+gates GEMM (M=16, N=96, K=1024) + routing epilogue
//            -> routed tile [16][96] bf16 in LDS
//   phase 2: out GEMM (M=16, N=3072, K=96); B prefetch in 2-tile groups,
//            TRIPLE-buffered (bb[3][6] = 72 VGPR, safely under the
//            128-VGPR cap from __launch_bounds__(256,2)), prefetch
//            distance 2 groups ~ L2 latency; loads issued BEFORE previous
//            group's stores (vmcnt decoupling); non-temporal f32 stores
//            (write stream must not sweep L2 -> lot stays L2-hot).
// ---------------------------------------------------------------------------
__global__ __launch_bounds__(256, 2) void k_fused(
    const float* __restrict__ x,     // [8192][1024] f32
    const ushort* __restrict__ wcat, // [96][1024] bf16
    const float* __restrict__ db,    // [84]
    const float* __restrict__ ntl,   // [84]
    const float* __restrict__ gb,    // [12]
    const int*   __restrict__ pi,    // [8][3]
    const float* __restrict__ pd,    // [8][3]
    const ushort* __restrict__ lot,  // [3][1024][96] bf16
    float* __restrict__ out)         // [3][8192][1024] f32
{
    __shared__ __attribute__((aligned(16))) char smem[30464];
    __shared__ __attribute__((aligned(16))) ushort rt[TOKPB][RSTR];
    __shared__ float invt[84];
    __shared__ float biasf[96];
    __shared__ int   pis[24];
    __shared__ float pds[24];

    ushort* xl = (ushort*)smem;                        // [16][XSTR] bf16
    ushort* wl = (ushort*)(smem + TOKPB * XSTR * 2);   // [96][XSTR] bf16
    float*  decis = (float*)smem;                      // [16][DSTR] f32 (reuse)
    float*  sdecs = (float*)(smem + TOKPB * DSTR * 4); // [16][SSTR] f32

    const int tid = threadIdx.x;
    const int tb  = blockIdx.x * TOKPB;

    if (tid < 84) {
        float z = ntl[tid] + 0.5413f;
        float sp = (z > 20.0f) ? z : log1pf(__expf(z));   // softplus
        invt[tid]  = 1.0f / sp;
        biasf[tid] = db[tid];
    } else if (tid < 96) {
        biasf[tid] = gb[tid - 84];
    } else if (tid < 120) {
        pis[tid - 96] = pi[tid - 96];
    } else if (tid < 144) {
        pds[tid - 120] = pd[tid - 120];
    }

    const int wave = tid >> 6, lane = tid & 63;
    const int lrow = lane & 15, quad = lane >> 4;

    // phase-1 N-tile ownership: wave0 {0,4}, wave1 {1,5}, wave2 {2}, wave3 {3}
    const int nt0 = wave;
    const bool two = (wave < 2);
    const int nt1 = wave + 4;

    floatx4 acc0 = (floatx4)(0.0f), acc1 = (floatx4)(0.0f);

    // register double-buffers for staged tiles
    floatx4 xv[2][2];
    uintx4  wv[2][6];

#define LOADX(B, KC) do { \
    _Pragma("unroll") for (int i_ = 0; i_ < 2; ++i_) { \
        int idx_ = tid + 256 * i_; \
        int r_ = idx_ >> 5, c_ = idx_ & 31; \
        xv[B][i_] = __builtin_nontemporal_load( \
            (const floatx4*)(x + (size_t)(tb + r_) * DIN + (KC) * 128 + c_ * 4)); \
    } } while (0)

#define LOADW(B, KC) do { \
    _Pragma("unroll") for (int i_ = 0; i_ < 6; ++i_) { \
        int idx_ = tid + 256 * i_; \
        int r_ = idx_ >> 4, c_ = idx_ & 15; \
        wv[B][i_] = *(const uintx4*)(wcat + r_ * DIN + (KC) * 128 + c_ * 8); \
    } } while (0)

#define STAGE(B) do { \
    _Pragma("unroll") for (int i_ = 0; i_ < 2; ++i_) { \
        int idx_ = tid + 256 * i_; \
        int r_ = idx_ >> 5, c_ = idx_ & 31; \
        uint2 p_; \
        p_.x = pack2(xv[B][i_][0], xv[B][i_][1]); \
        p_.y = pack2(xv[B][i_][2], xv[B][i_][3]); \
        *(uint2*)(xl + r_ * XSTR + c_ * 4) = p_; \
    } \
    _Pragma("unroll") for (int i_ = 0; i_ < 6; ++i_) { \
        int idx_ = tid + 256 * i_; \
        int r_ = idx_ >> 4, c_ = idx_ & 15; \
        *(uintx4*)(wl + r_ * XSTR + c_ * 8) = wv[B][i_]; \
    } } while (0)

    LOADX(0, 0);
    LOADW(0, 0);

#pragma unroll
    for (int kc = 0; kc < 8; ++kc) {
        const int cur = kc & 1, nxt = cur ^ 1;
        __syncthreads();            // previous iter's ds_reads complete
        STAGE(cur);
        __syncthreads();
        if (kc < 7) {               // issue next tile's loads early
            LOADX(nxt, kc + 1);
            LOADW(nxt, kc + 1);
        }

        short8 a[4];
#pragma unroll
        for (int kt = 0; kt < 4; ++kt)
            a[kt] = *(const short8*)(xl + lrow * XSTR + kt * 32 + quad * 8);
#pragma unroll
        for (int kt = 0; kt < 4; ++kt) {
            short8 b0 = *(const short8*)(wl + (nt0 * 16 + lrow) * XSTR + kt * 32 + quad * 8);
            acc0 = __builtin_amdgcn_mfma_f32_16x16x32_bf16(a[kt], b0, acc0, 0, 0, 0);
        }
        if (two) {
#pragma unroll
            for (int kt = 0; kt < 4; ++kt) {
                short8 b1 = *(const short8*)(wl + (nt1 * 16 + lrow) * XSTR + kt * 32 + quad * 8);
                acc1 = __builtin_amdgcn_mfma_f32_16x16x32_bf16(a[kt], b1, acc1, 0, 0, 0);
            }
        }
    }
#undef LOADX
#undef LOADW
#undef STAGE

    __syncthreads();
    // C/D: col = lane&15 (j within 16-tile), row = quad*4+reg (token)
#pragma unroll
    for (int r = 0; r < 4; ++r)
        decis[(quad * 4 + r) * DSTR + nt0 * 16 + lrow] = acc0[r];
    if (two) {
#pragma unroll
        for (int r = 0; r < 4; ++r)
            decis[(quad * 4 + r) * DSTR + nt1 * 16 + lrow] = acc1[r];
    }
    __syncthreads();

    // stage 1: sigmoid over 16 tokens x 84 nodes = 1344
#pragma unroll
    for (int i = 0; i < 6; ++i) {
        int idx = tid + 256 * i;
        if (idx < TOKPB * 84) {
            int tk = idx / 84, nd = idx - tk * 84;
            float dv = (decis[tk * DSTR + nd] + biasf[nd]) * invt[nd];
            sdecs[tk * SSTR + nd] = 1.0f / (1.0f + __expf(-dv));
        }
    }
    __syncthreads();

    // stage 2: 256 threads = 16 tokens x 8 leaves x 2 tree-halves -> rt in LDS
    {
        const int tk = tid >> 4, l = (tid >> 1) & 7, th = tid & 1;
        float g[12], gm = -1e30f;
#pragma unroll
        for (int tt = 0; tt < 12; ++tt) {
            g[tt] = decis[tk * DSTR + 84 + tt] + biasf[84 + tt];
            gm = fmaxf(gm, g[tt]);
        }
        float gs = 0.0f;
#pragma unroll
        for (int tt = 0; tt < 12; ++tt) { g[tt] = __expf(g[tt] - gm); gs += g[tt]; }
        float ginv = 1.0f / gs;

        const int   n0 = pis[l * 3 + 0], n1 = pis[l * 3 + 1], n2 = pis[l * 3 + 2];
        const float d0 = pds[l * 3 + 0], d1 = pds[l * 3 + 1], d2 = pds[l * 3 + 2];
        const float* sd = sdecs + tk * SSTR;
        const int t0 = th * 6;
#pragma unroll
        for (int t = 0; t < 6; ++t) {
            int tt = t0 + t;
            float s0 = sd[tt * 7 + n0], s1 = sd[tt * 7 + n1], s2 = sd[tt * 7 + n2];
            float pb = g[tt] * ginv
                     * (d0 * s0 + (1.0f - d0) * (1.0f - s0))
                     * (d1 * s1 + (1.0f - d1) * (1.0f - s1))
                     * (d2 * s2 + (1.0f - d2) * (1.0f - s2));
            rt[tk][tt * 8 + l] = f2b(pb);
        }
    }
    __syncthreads();

    // ------------------------------------------------------------------
    // phase 2: out GEMM.  Each wave owns 768 columns (48 16-col tiles =
    // 24 groups of 2) of the 3072-wide (3 heads x 1024) output.
    // Triple-buffered B prefetch, distance 2 groups (~L2 latency);
    // group g+2 loads issued BEFORE group g's stores.  Fully unrolled
    // => all buffer indices static (no scratch).
    // ------------------------------------------------------------------
    {
        short8 a[3];
#pragma unroll
        for (int kk = 0; kk < 3; ++kk)
            a[kk] = *(const short8*)(&rt[lrow][quad * 8 + kk * 32]);

        short8 bb[3][6];
#define LOADB(B, G) do { \
    _Pragma("unroll") for (int q_ = 0; q_ < 2; ++q_) { \
        int c_ = wave * 768 + ((G) * 2 + q_) * 16; \
        int h_ = c_ >> 10; \
        int d_ = (c_ & 1023) + lrow; \
        const ushort* bp_ = lot + (size_t)h_ * LOT_H + (size_t)d_ * NJ + quad * 8; \
        _Pragma("unroll") for (int kk_ = 0; kk_ < 3; ++kk_) \
            bb[B][q_ * 3 + kk_] = *(const short8*)(bp_ + kk_ * 32); \
    } } while (0)

        LOADB(0, 0);
        LOADB(1, 1);
#pragma unroll
        for (int g = 0; g < 24; ++g) {
            const int cur = g % 3;
            if (g < 22) LOADB((g + 2) % 3, g + 2);
#pragma unroll
            for (int q = 0; q < 2; ++q) {
                floatx4 c0 = (floatx4)(0.0f);
#pragma unroll
                for (int kk = 0; kk < 3; ++kk)
                    c0 = __builtin_amdgcn_mfma_f32_16x16x32_bf16(a[kk], bb[cur][q * 3 + kk], c0, 0, 0, 0);
                int c = wave * 768 + (g * 2 + q) * 16;
                int h = c >> 10;
                int d = (c & 1023) + lrow;
                float* ob = out + ((size_t)h * NTOK + tb) * DOUT + d;
#pragma unroll
                for (int r = 0; r < 4; ++r)
                    __builtin_nontemporal_store(c0[r], ob + (size_t)(quad * 4 + r) * DOUT);
            }
        }
#undef LOADB
    }
}

// ---------------------------------------------------------------------------
extern "C" void kernel_launch(void* const* d_in, const int* in_sizes, int n_in,
                              void* d_out, int out_size, void* d_ws, size_t ws_size,
                              hipStream_t stream) {
    const float* x   = (const float*)d_in[0];
    const float* dw  = (const float*)d_in[1];
    const float* db  = (const float*)d_in[2];
    const float* ntl = (const float*)d_in[3];
    const float* gw  = (const float*)d_in[4];
    const float* gb  = (const float*)d_in[5];
    const float* lo  = (const float*)d_in[6];
    const int*   pi  = (const int*)d_in[7];
    const float* pd  = (const float*)d_in[8];
    float* out = (float*)d_out;

    ushort* lot  = (ushort*)d_ws;                 // 3*98304*2 = 0.59 MB
    ushort* wcat = lot + (size_t)3 * LOT_H;       // 96*1024*2 = 0.20 MB

    k_prep<<<dim3((3 * LOT_H + NJ * DIN) / 256), dim3(256), 0, stream>>>(lo, dw, gw, lot, wcat);
    k_fused<<<dim3(NTOK / TOKPB), dim3(256), 0, stream>>>(x, wcat, db, ntl, gb, pi, pd, lot, out);
}